// Round 1
// baseline (1383.966 us; speedup 1.0000x reference)
//
#include <hip/hip_runtime.h>
#include <cmath>

#define B_TOTAL 65536
#define TM      16      // rows per block
#define D1      32
#define D2      32
#define DFF     256
#define DOUT    1568
#define NB      16      // spline bins
#define PPD     49      // params per output dim (16w + 16h + 17d)
#define CDIMS   8       // dims per GEMM3/spline chunk
#define CCOLS   (CDIMS * PPD)   // 392
#define NCHUNK  (D2 / CDIMS)    // 4
#define TAILV   3.0f
#define MINV    0.001f
#define CSC     0.984f  // 1 - NB*MINV

__device__ __forceinline__ float softplus_f(float x) {
    return (x > 20.0f) ? x : log1pf(expf(x));
}

extern "C" __global__ void __launch_bounds__(256, 2)
rq_fused(const float* __restrict__ x1, const float* __restrict__ x2,
         const float* __restrict__ W1, const float* __restrict__ b1,
         const float* __restrict__ W2, const float* __restrict__ b2,
         const float* __restrict__ W3, const float* __restrict__ b3,
         float* __restrict__ zout, float* __restrict__ ldout)
{
    __shared__ float sX1[TM][D1];
    __shared__ float sX2[TM][D2];
    __shared__ float sH1[TM][DFF];
    __shared__ float sH2[TM][DFF];
    __shared__ float sP [TM][CCOLS];
    __shared__ float sLD[TM][D2];

    const int tid  = threadIdx.x;
    const int row0 = blockIdx.x * TM;

    // ---- stage x1, x2 tiles (TM*32 floats each) ----
    if (tid < (TM * D1) / 4) {
        const float4* xv1 = reinterpret_cast<const float4*>(x1 + (size_t)row0 * D1);
        const float4* xv2 = reinterpret_cast<const float4*>(x2 + (size_t)row0 * D2);
        reinterpret_cast<float4*>(&sX1[0][0])[tid] = xv1[tid];
        reinterpret_cast<float4*>(&sX2[0][0])[tid] = xv2[tid];
    }
    __syncthreads();

    // ---- GEMM1: h1 = relu(x1 @ W1 + b1), micro-tile 2 rows x 8 cols ----
    {
        const int r0 = (tid >> 5) << 1;
        const int c0 = (tid & 31) << 3;
        float acc[2][8];
        #pragma unroll
        for (int r = 0; r < 2; ++r)
            #pragma unroll
            for (int c = 0; c < 8; ++c) acc[r][c] = 0.0f;

        #pragma unroll
        for (int i = 0; i < D1; i += 4) {
            float a0[4], a1[4];
            *reinterpret_cast<float4*>(a0) = *reinterpret_cast<const float4*>(&sX1[r0][i]);
            *reinterpret_cast<float4*>(a1) = *reinterpret_cast<const float4*>(&sX1[r0 + 1][i]);
            #pragma unroll
            for (int m = 0; m < 4; ++m) {
                const float* wr = W1 + (size_t)(i + m) * DFF + c0;
                float w[8];
                *reinterpret_cast<float4*>(w)     = *reinterpret_cast<const float4*>(wr);
                *reinterpret_cast<float4*>(w + 4) = *reinterpret_cast<const float4*>(wr + 4);
                #pragma unroll
                for (int c = 0; c < 8; ++c) {
                    acc[0][c] = fmaf(a0[m], w[c], acc[0][c]);
                    acc[1][c] = fmaf(a1[m], w[c], acc[1][c]);
                }
            }
        }
        float bb[8];
        *reinterpret_cast<float4*>(bb)     = *reinterpret_cast<const float4*>(b1 + c0);
        *reinterpret_cast<float4*>(bb + 4) = *reinterpret_cast<const float4*>(b1 + c0 + 4);
        #pragma unroll
        for (int r = 0; r < 2; ++r) {
            float o[8];
            #pragma unroll
            for (int c = 0; c < 8; ++c) o[c] = fmaxf(acc[r][c] + bb[c], 0.0f);
            *reinterpret_cast<float4*>(&sH1[r0 + r][c0])     = *reinterpret_cast<float4*>(o);
            *reinterpret_cast<float4*>(&sH1[r0 + r][c0 + 4]) = *reinterpret_cast<float4*>(o + 4);
        }
    }
    __syncthreads();

    // ---- GEMM2: h2 = relu(h1 @ W2 + b2), micro-tile 2 rows x 8 cols, K=256 ----
    {
        const int r0 = (tid >> 5) << 1;
        const int c0 = (tid & 31) << 3;
        float acc[2][8];
        #pragma unroll
        for (int r = 0; r < 2; ++r)
            #pragma unroll
            for (int c = 0; c < 8; ++c) acc[r][c] = 0.0f;

        #pragma unroll 2
        for (int i = 0; i < DFF; i += 4) {
            float a0[4], a1[4];
            *reinterpret_cast<float4*>(a0) = *reinterpret_cast<const float4*>(&sH1[r0][i]);
            *reinterpret_cast<float4*>(a1) = *reinterpret_cast<const float4*>(&sH1[r0 + 1][i]);
            #pragma unroll
            for (int m = 0; m < 4; ++m) {
                const float* wr = W2 + (size_t)(i + m) * DFF + c0;
                float w[8];
                *reinterpret_cast<float4*>(w)     = *reinterpret_cast<const float4*>(wr);
                *reinterpret_cast<float4*>(w + 4) = *reinterpret_cast<const float4*>(wr + 4);
                #pragma unroll
                for (int c = 0; c < 8; ++c) {
                    acc[0][c] = fmaf(a0[m], w[c], acc[0][c]);
                    acc[1][c] = fmaf(a1[m], w[c], acc[1][c]);
                }
            }
        }
        float bb[8];
        *reinterpret_cast<float4*>(bb)     = *reinterpret_cast<const float4*>(b2 + c0);
        *reinterpret_cast<float4*>(bb + 4) = *reinterpret_cast<const float4*>(b2 + c0 + 4);
        #pragma unroll
        for (int r = 0; r < 2; ++r) {
            float o[8];
            #pragma unroll
            for (int c = 0; c < 8; ++c) o[c] = fmaxf(acc[r][c] + bb[c], 0.0f);
            *reinterpret_cast<float4*>(&sH2[r0 + r][c0])     = *reinterpret_cast<float4*>(o);
            *reinterpret_cast<float4*>(&sH2[r0 + r][c0 + 4]) = *reinterpret_cast<float4*>(o + 4);
        }
    }
    __syncthreads();

    // ---- GEMM3 chunk (8 dims = 392 cols) + fused spline ----
    for (int ch = 0; ch < NCHUNK; ++ch) {
        if (tid < 196) {
            const int rg = (tid / 49) * 4;          // 4 rows
            const int cl = (tid % 49) * 8;          // 8 cols, local in chunk
            const int cg = ch * CCOLS + cl;         // global col in [0,1568)
            float acc[4][8];
            #pragma unroll
            for (int r = 0; r < 4; ++r)
                #pragma unroll
                for (int c = 0; c < 8; ++c) acc[r][c] = 0.0f;

            #pragma unroll 2
            for (int i = 0; i < DFF; i += 4) {
                float a[4][4];
                #pragma unroll
                for (int r = 0; r < 4; ++r)
                    *reinterpret_cast<float4*>(a[r]) =
                        *reinterpret_cast<const float4*>(&sH2[rg + r][i]);
                #pragma unroll
                for (int m = 0; m < 4; ++m) {
                    const float* wr = W3 + (size_t)(i + m) * DOUT + cg;
                    float w[8];
                    *reinterpret_cast<float4*>(w)     = *reinterpret_cast<const float4*>(wr);
                    *reinterpret_cast<float4*>(w + 4) = *reinterpret_cast<const float4*>(wr + 4);
                    #pragma unroll
                    for (int r = 0; r < 4; ++r)
                        #pragma unroll
                        for (int c = 0; c < 8; ++c)
                            acc[r][c] = fmaf(a[r][m], w[c], acc[r][c]);
                }
            }
            float bb[8];
            *reinterpret_cast<float4*>(bb)     = *reinterpret_cast<const float4*>(b3 + cg);
            *reinterpret_cast<float4*>(bb + 4) = *reinterpret_cast<const float4*>(b3 + cg + 4);
            #pragma unroll
            for (int r = 0; r < 4; ++r) {
                float o[8];
                #pragma unroll
                for (int c = 0; c < 8; ++c) o[c] = acc[r][c] + bb[c];
                *reinterpret_cast<float4*>(&sP[rg + r][cl])     = *reinterpret_cast<float4*>(o);
                *reinterpret_cast<float4*>(&sP[rg + r][cl + 4]) = *reinterpret_cast<float4*>(o + 4);
            }
        }
        __syncthreads();

        // ---- spline for 16 rows x 8 dims ----
        if (tid < TM * CDIMS) {
            const int r   = tid >> 3;
            const int jj  = tid & 7;
            const int dim = ch * CDIMS + jj;
            const float* pp = &sP[r][jj * PPD];
            const float x  = sX2[r][dim];
            const float xc = fminf(fmaxf(x, -TAILV), TAILV);

            // widths: softmax -> affine -> cumulative; find bin + edges in one pass
            float e[NB];
            float mx = -1e30f;
            #pragma unroll
            for (int k = 0; k < NB; ++k) mx = fmaxf(mx, pp[k]);
            float s = 0.0f;
            #pragma unroll
            for (int k = 0; k < NB; ++k) { e[k] = expf(pp[k] - mx); s += e[k]; }
            const float inv = 1.0f / s;

            int   idx = 0;
            float xk  = -TAILV, xk1 = TAILV;
            float cum = 0.0f;
            #pragma unroll
            for (int k = 0; k < NB; ++k) {
                const float lo = -TAILV + 2.0f * TAILV * cum;   // cumw[k]
                cum += MINV + CSC * e[k] * inv;
                const float hi = -TAILV + 2.0f * TAILV * cum;   // cumw[k+1]
                if (lo <= xc) { idx = k; xk = lo; xk1 = hi; }   // last k with lower edge <= xc
            }

            // heights: softmax -> extract cumh[idx], cumh[idx+1]
            float mh = -1e30f;
            #pragma unroll
            for (int k = 0; k < NB; ++k) mh = fmaxf(mh, pp[NB + k]);
            float sh = 0.0f;
            float eh[NB];
            #pragma unroll
            for (int k = 0; k < NB; ++k) { eh[k] = expf(pp[NB + k] - mh); sh += eh[k]; }
            const float invh = 1.0f / sh;

            float yk = -TAILV, yk1 = TAILV;
            cum = 0.0f;
            #pragma unroll
            for (int k = 0; k < NB; ++k) {
                const float lo = -TAILV + 2.0f * TAILV * cum;
                cum += MINV + CSC * eh[k] * invh;
                const float hi = -TAILV + 2.0f * TAILV * cum;
                if (k == idx) { yk = lo; yk1 = hi; }
            }

            const float d0 = MINV + softplus_f(pp[2 * NB + idx]);
            const float d1 = MINV + softplus_f(pp[2 * NB + idx + 1]);

            const float wd  = xk1 - xk;
            const float hd  = yk1 - yk;
            const float sk  = hd / wd;
            const float xi  = (xc - xk) / wd;
            const float xim = xi * (1.0f - xi);
            const float alpha = hd * (sk * xi * xi + d0 * xim);
            const float beta  = sk + (d1 + d0 - 2.0f * sk) * xim;
            const float z     = yk + alpha / beta;
            const float om    = 1.0f - xi;
            const float dn    = sk * sk * (d1 * xi * xi + 2.0f * sk * xim + d0 * om * om);
            const float ld    = logf(dn) - 2.0f * logf(beta);

            const bool inside = (x >= -TAILV) && (x <= TAILV);
            zout[(size_t)(row0 + r) * D2 + dim] = inside ? z : x;
            sLD[r][dim] = inside ? ld : 0.0f;
        }
        __syncthreads();   // protect sP before next chunk overwrites it
    }

    // ---- reduce log_det over dims ----
    if (tid < TM) {
        float sld = 0.0f;
        #pragma unroll
        for (int j = 0; j < D2; ++j) sld += sLD[tid][j];
        ldout[row0 + tid] = sld;
    }
}

extern "C" void kernel_launch(void* const* d_in, const int* in_sizes, int n_in,
                              void* d_out, int out_size, void* d_ws, size_t ws_size,
                              hipStream_t stream)
{
    const float* x1 = (const float*)d_in[0];
    const float* x2 = (const float*)d_in[1];
    const float* W1 = (const float*)d_in[2];
    const float* b1 = (const float*)d_in[3];
    const float* W2 = (const float*)d_in[4];
    const float* b2 = (const float*)d_in[5];
    const float* W3 = (const float*)d_in[6];
    const float* b3 = (const float*)d_in[7];

    float* zout  = (float*)d_out;                       // (65536, 32)
    float* ldout = zout + (size_t)B_TOTAL * D2;         // (65536,)

    dim3 grid(B_TOTAL / TM);
    rq_fused<<<grid, 256, 0, stream>>>(x1, x2, W1, b1, W2, b2, W3, b3, zout, ldout);
}

// Round 6
// 369.500 us; speedup vs baseline: 3.7455x; 3.7455x over previous
//
#include <hip/hip_runtime.h>
#include <cmath>

#define NB 16
#define TAILV 3.0f
#define MINV 0.001f
#define CSC 0.984f   // 1 - NB*MINV

typedef __attribute__((ext_vector_type(8))) _Float16 half8;
typedef __attribute__((ext_vector_type(4))) float f32x4;

#define MFMA16(a,b,c) __builtin_amdgcn_mfma_f32_16x16x32_f16(a,b,c,0,0,0)

__device__ __forceinline__ ushort f2h(float f) {
    union { _Float16 h; ushort u; } v; v.h = (_Float16)f; return v.u;
}
__device__ __forceinline__ float softplus_f(float x) {
    return (x > 20.0f) ? x : log1pf(expf(x));
}

// ---- prologue: convert/transpose weights into d_ws (fp16, [N][K]) ----
// W3T: [2048][256], n = dim*64 + p (p<49 real, else 0).  W2T: [256][256].  W1T: [256][32].
__global__ void __launch_bounds__(256)
cvt_weights(const float* __restrict__ W1, const float* __restrict__ W2,
            const float* __restrict__ W3, const float* __restrict__ b3,
            ushort* __restrict__ W3T, ushort* __restrict__ W2T,
            ushort* __restrict__ W1T, float* __restrict__ b3p)
{
    const int b = blockIdx.x, t = threadIdx.x;
    if (b < 2048) {
        int idx = b * 256 + t;
        int n = idx >> 8, k = idx & 255;
        int dim = n >> 6, p = n & 63;
        float v = (p < 49) ? W3[(size_t)k * 1568 + dim * 49 + p] : 0.0f;
        W3T[idx] = f2h(v);
        if (k == 0) b3p[n] = (p < 49) ? b3[dim * 49 + p] : 0.0f;
    } else if (b < 2048 + 256) {
        int idx = (b - 2048) * 256 + t;
        int n = idx >> 8, k = idx & 255;
        W2T[idx] = f2h(W2[(size_t)k * 256 + n]);
    } else {   // 32 blocks for W1 (8192 elems)
        int idx = (b - 2304) * 256 + t;
        int n = idx >> 5, k = idx & 31;
        W1T[idx] = f2h(W1[(size_t)k * 256 + n]);
    }
}

// ---- fused main kernel: 32 batch rows / block, 4 waves ----
// LDS overlay: sA1|sH1|sH2 (phases 1-3) share the region reused as fp32 sPw (phase 4).
extern "C" __global__ void __launch_bounds__(256, 2)
rq_mfma(const float* __restrict__ x1, const float* __restrict__ x2,
        const float* __restrict__ b1, const float* __restrict__ b2,
        const ushort* __restrict__ W1T, const ushort* __restrict__ W2T,
        const ushort* __restrict__ W3T, const float* __restrict__ b3p,
        float* __restrict__ zout, float* __restrict__ ldout)
{
    __shared__ char smem[60160];
    float*  sX2 = (float*)smem;                     // [32][33] f32
    float*  sLD = (float*)(smem + 4224);            // [32][33] f32
    char*   U   = smem + 8448;                      // 51712-byte union
    ushort* sA1 = (ushort*)U;                       // [32][40] fp16
    ushort* sH1 = (ushort*)(U + 2560);              // [32][264] fp16
    ushort* sH2 = (ushort*)(U + 2560 + 16896);      // [32][264] fp16
    float*  sPw = (float*)U;                        // 4 x [32][101] f32 (phase 4)

    const int tid  = threadIdx.x;
    const int row0 = blockIdx.x * 32;
    const int wave = tid >> 6, lane = tid & 63;
    const int ln = lane & 15, kg = lane >> 4;       // A/B frag: m/n=ln, k-group=kg

    // ---- phase 0: stage x1 (->fp16) and x2 (f32) ----
    {
        int r = tid >> 3, c = (tid & 7) << 2;
        float4 v = *(const float4*)(x1 + (size_t)(row0 + r) * 32 + c);
        sA1[r*40 + c    ] = f2h(v.x);
        sA1[r*40 + c + 1] = f2h(v.y);
        sA1[r*40 + c + 2] = f2h(v.z);
        sA1[r*40 + c + 3] = f2h(v.w);
        float4 w = *(const float4*)(x2 + (size_t)(row0 + r) * 32 + c);
        sX2[r*33 + c] = w.x; sX2[r*33 + c + 1] = w.y;
        sX2[r*33 + c + 2] = w.z; sX2[r*33 + c + 3] = w.w;
    }
    __syncthreads();

    // ---- phase 1: h1 = relu(x1 @ W1 + b1); K=32 = one MFMA ----
    {
        half8 a0 = *(const half8*)(sA1 + ln * 40 + kg * 8);
        half8 a1 = *(const half8*)(sA1 + (16 + ln) * 40 + kg * 8);
        #pragma unroll
        for (int nt = 0; nt < 4; ++nt) {
            int n = wave * 64 + nt * 16 + ln;
            half8 bfr = *(const half8*)(W1T + n * 32 + kg * 8);
            f32x4 zr = {0.f, 0.f, 0.f, 0.f};
            f32x4 c0 = MFMA16(a0, bfr, zr);
            f32x4 c1 = MFMA16(a1, bfr, zr);
            float bias = b1[n];
            #pragma unroll
            for (int g = 0; g < 4; ++g) {
                sH1[(kg*4 + g) * 264 + n]      = f2h(fmaxf(c0[g] + bias, 0.f));
                sH1[(16 + kg*4 + g) * 264 + n] = f2h(fmaxf(c1[g] + bias, 0.f));
            }
        }
    }
    __syncthreads();

    // ---- phase 2: h2 = relu(h1 @ W2 + b2); K=256 ----
    {
        half8 a0[8], a1[8];
        #pragma unroll
        for (int ks = 0; ks < 8; ++ks) {
            a0[ks] = *(const half8*)(sH1 + ln * 264 + ks * 32 + kg * 8);
            a1[ks] = *(const half8*)(sH1 + (16 + ln) * 264 + ks * 32 + kg * 8);
        }
        #pragma unroll
        for (int nt = 0; nt < 4; ++nt) {
            int n = wave * 64 + nt * 16 + ln;
            f32x4 c0 = {0,0,0,0}, c1 = {0,0,0,0};
            const ushort* bp = W2T + (size_t)n * 256 + kg * 8;
            #pragma unroll
            for (int ks = 0; ks < 8; ++ks) {
                half8 bfr = *(const half8*)(bp + ks * 32);
                c0 = MFMA16(a0[ks], bfr, c0);
                c1 = MFMA16(a1[ks], bfr, c1);
            }
            float bias = b2[n];
            #pragma unroll
            for (int g = 0; g < 4; ++g) {
                sH2[(kg*4 + g) * 264 + n]      = f2h(fmaxf(c0[g] + bias, 0.f));
                sH2[(16 + kg*4 + g) * 264 + n] = f2h(fmaxf(c1[g] + bias, 0.f));
            }
        }
    }
    __syncthreads();

    // ---- phase 3: hoist GEMM3 A-fragments to registers, free sH2 for sPw ----
    half8 A0[8], A1[8];
    #pragma unroll
    for (int ks = 0; ks < 8; ++ks) {
        A0[ks] = *(const half8*)(sH2 + ln * 264 + ks * 32 + kg * 8);
        A1[ks] = *(const half8*)(sH2 + (16 + ln) * 264 + ks * 32 + kg * 8);
    }
    __syncthreads();

    // ---- phase 4: GEMM3 (N padded 2048, 64 cols/dim) + fused spline ----
    // wave owns dims [wave*8, wave*8+8); 2 dims (8 N-tiles) per chunk.
    // params stored fp32: [32 rows][101] per wave, dim offset 50, cols p<49 kept.
    float* myP = sPw + wave * (32 * 101);
    for (int dc = 0; dc < 4; ++dc) {
        const int nb = (wave * 8 + dc * 2) * 64;
        #pragma unroll 2
        for (int nt = 0; nt < 8; ++nt) {
            int n = nb + nt * 16 + ln;
            float bias = b3p[n];
            f32x4 c0 = {0,0,0,0}, c1 = {0,0,0,0};
            const ushort* bp = W3T + (size_t)n * 256 + kg * 8;
            #pragma unroll
            for (int ks = 0; ks < 8; ++ks) {
                half8 bfr = *(const half8*)(bp + ks * 32);
                c0 = MFMA16(A0[ks], bfr, c0);
                c1 = MFMA16(A1[ks], bfr, c1);
            }
            int lc = nt * 16 + ln;
            int dd = lc >> 6, p = lc & 63;
            if (p < 49) {
                #pragma unroll
                for (int g = 0; g < 4; ++g) {
                    myP[(kg*4 + g) * 101 + dd * 50 + p]      = c0[g] + bias;
                    myP[(16 + kg*4 + g) * 101 + dd * 50 + p] = c1[g] + bias;
                }
            }
        }
        __syncthreads();

        // spline: 32 rows x 2 dims = 1 task/lane, wave-local fp32 params
        {
            const int r = lane >> 1, dd = lane & 1;
            const int dim = wave * 8 + dc * 2 + dd;
            const float* pp = myP + r * 101 + dd * 50;
            const float x  = sX2[r * 33 + dim];
            const float xc = fminf(fmaxf(x, -TAILV), TAILV);

            float e[NB]; float mx = -1e30f;
            #pragma unroll
            for (int k = 0; k < NB; ++k) { e[k] = pp[k]; mx = fmaxf(mx, e[k]); }
            float s = 0.f;
            #pragma unroll
            for (int k = 0; k < NB; ++k) { e[k] = expf(e[k] - mx); s += e[k]; }
            const float inv = 1.f / s;

            int idx = 0; float xk = -TAILV, xk1 = TAILV, cum = 0.f;
            #pragma unroll
            for (int k = 0; k < NB; ++k) {
                float lo = -TAILV + 2.f * TAILV * cum;
                cum += MINV + CSC * e[k] * inv;
                float hi = -TAILV + 2.f * TAILV * cum;
                if (lo <= xc) { idx = k; xk = lo; xk1 = hi; }
            }

            float eh[NB]; float mh = -1e30f;
            #pragma unroll
            for (int k = 0; k < NB; ++k) { eh[k] = pp[NB + k]; mh = fmaxf(mh, eh[k]); }
            float sh = 0.f;
            #pragma unroll
            for (int k = 0; k < NB; ++k) { eh[k] = expf(eh[k] - mh); sh += eh[k]; }
            const float invh = 1.f / sh;

            float yk = -TAILV, yk1 = TAILV; cum = 0.f;
            #pragma unroll
            for (int k = 0; k < NB; ++k) {
                float lo = -TAILV + 2.f * TAILV * cum;
                cum += MINV + CSC * eh[k] * invh;
                float hi = -TAILV + 2.f * TAILV * cum;
                if (k == idx) { yk = lo; yk1 = hi; }
            }

            const float d0 = MINV + softplus_f(pp[2 * NB + idx]);
            const float d1 = MINV + softplus_f(pp[2 * NB + idx + 1]);

            const float wd = xk1 - xk, hd = yk1 - yk;
            const float sk = hd / wd;
            const float xi = (xc - xk) / wd;
            const float xim = xi * (1.f - xi);
            const float alpha = hd * (sk * xi * xi + d0 * xim);
            const float beta  = sk + (d1 + d0 - 2.f * sk) * xim;
            const float z     = yk + alpha / beta;
            const float om    = 1.f - xi;
            const float dn    = sk * sk * (d1 * xi * xi + 2.f * sk * xim + d0 * om * om);
            const float ld    = logf(dn) - 2.f * logf(beta);

            const bool inside = (x >= -TAILV) && (x <= TAILV);
            zout[(size_t)(row0 + r) * 32 + dim] = inside ? z : x;
            sLD[r * 33 + dim] = inside ? ld : 0.f;
        }
        __syncthreads();
    }

    // ---- phase 5: log_det reduction ----
    if (tid < 32) {
        float sld = 0.f;
        #pragma unroll
        for (int j = 0; j < 32; ++j) sld += sLD[tid * 33 + j];
        ldout[row0 + tid] = sld;
    }
}

extern "C" void kernel_launch(void* const* d_in, const int* in_sizes, int n_in,
                              void* d_out, int out_size, void* d_ws, size_t ws_size,
                              hipStream_t stream)
{
    const float* x1 = (const float*)d_in[0];
    const float* x2 = (const float*)d_in[1];
    const float* W1 = (const float*)d_in[2];
    const float* b1 = (const float*)d_in[3];
    const float* W2 = (const float*)d_in[4];
    const float* b2 = (const float*)d_in[5];
    const float* W3 = (const float*)d_in[6];
    const float* b3 = (const float*)d_in[7];

    // d_ws layout (1,204,224 B total)
    ushort* W3T = (ushort*)d_ws;                 // 2048*256 fp16 = 1 MB
    ushort* W2T = W3T + 2048 * 256;              // 256*256 fp16
    ushort* W1T = W2T + 256 * 256;               // 256*32 fp16
    float*  b3p = (float*)(W1T + 256 * 32);      // 2048 f32

    float* zout  = (float*)d_out;                // (65536, 32)
    float* ldout = zout + (size_t)65536 * 32;    // (65536,)

    cvt_weights<<<2336, 256, 0, stream>>>(W1, W2, W3, b3, W3T, W2T, W1T, b3p);
    rq_mfma<<<2048, 256, 0, stream>>>(x1, x2, b1, b2, W1T, W2T, W3T, b3p, zout, ldout);
}

// Round 8
// 354.141 us; speedup vs baseline: 3.9080x; 1.0434x over previous
//
#include <hip/hip_runtime.h>
#include <cmath>

#define NB 16
#define TAILV 3.0f
#define MINV 0.001f
#define CSC 0.984f   // 1 - NB*MINV

typedef __attribute__((ext_vector_type(8))) _Float16 half8;
typedef __attribute__((ext_vector_type(4))) float f32x4;

#define MFMA16(a,b,c) __builtin_amdgcn_mfma_f32_16x16x32_f16(a,b,c,0,0,0)

__device__ __forceinline__ ushort f2h(float f) {
    union { _Float16 h; ushort u; } v; v.h = (_Float16)f; return v.u;
}
__device__ __forceinline__ float softplus_f(float x) {
    return (x > 20.0f) ? x : log1pf(expf(x));
}

// ---- prologue: convert/transpose weights into d_ws (fp16, [N][K]) ----
// W3T: [2048][256], n = dim*64 + p (p<49 real, else 0).  W2T: [256][256].  W1T: [256][32].
__global__ void __launch_bounds__(256)
cvt_weights(const float* __restrict__ W1, const float* __restrict__ W2,
            const float* __restrict__ W3, const float* __restrict__ b3,
            ushort* __restrict__ W3T, ushort* __restrict__ W2T,
            ushort* __restrict__ W1T, float* __restrict__ b3p)
{
    const int b = blockIdx.x, t = threadIdx.x;
    if (b < 2048) {
        int idx = b * 256 + t;
        int n = idx >> 8, k = idx & 255;
        int dim = n >> 6, p = n & 63;
        float v = (p < 49) ? W3[(size_t)k * 1568 + dim * 49 + p] : 0.0f;
        W3T[idx] = f2h(v);
        if (k == 0) b3p[n] = (p < 49) ? b3[dim * 49 + p] : 0.0f;
    } else if (b < 2048 + 256) {
        int idx = (b - 2048) * 256 + t;
        int n = idx >> 8, k = idx & 255;
        W2T[idx] = f2h(W2[(size_t)k * 256 + n]);
    } else {   // 32 blocks for W1 (8192 elems)
        int idx = (b - 2304) * 256 + t;
        int n = idx >> 5, k = idx & 31;
        W1T[idx] = f2h(W1[(size_t)k * 256 + n]);
    }
}

// ---- fused main kernel: 32 batch rows / block, 4 waves ----
// LDS overlay: sA1|sH1|sH2 (phases 1-3) share the region reused as fp32 sPw (phase 4).
// Phase 4 has NO barriers: myP/sLD/zout accesses are wave-private or disjoint,
// DS ops are in-order per wave — waves stream independently (MFMA/VALU co-issue).
extern "C" __global__ void __launch_bounds__(256, 2)
rq_mfma(const float* __restrict__ x1, const float* __restrict__ x2,
        const float* __restrict__ b1, const float* __restrict__ b2,
        const ushort* __restrict__ W1T, const ushort* __restrict__ W2T,
        const ushort* __restrict__ W3T, const float* __restrict__ b3p,
        float* __restrict__ zout, float* __restrict__ ldout)
{
    __shared__ char smem[60160];
    float*  sX2 = (float*)smem;                     // [32][33] f32
    float*  sLD = (float*)(smem + 4224);            // [32][33] f32
    char*   U   = smem + 8448;                      // 51712-byte union
    ushort* sA1 = (ushort*)U;                       // [32][40] fp16
    ushort* sH1 = (ushort*)(U + 2560);              // [32][264] fp16
    ushort* sH2 = (ushort*)(U + 2560 + 16896);      // [32][264] fp16
    float*  sPw = (float*)U;                        // 4 x [32][101] f32 (phase 4)

    const int tid  = threadIdx.x;
    const int row0 = blockIdx.x * 32;
    const int wave = tid >> 6, lane = tid & 63;
    const int ln = lane & 15, kg = lane >> 4;       // A/B frag: m/n=ln, k-group=kg

    // ---- phase 0: stage x1 (->fp16) and x2 (f32) ----
    {
        int r = tid >> 3, c = (tid & 7) << 2;
        float4 v = *(const float4*)(x1 + (size_t)(row0 + r) * 32 + c);
        sA1[r*40 + c    ] = f2h(v.x);
        sA1[r*40 + c + 1] = f2h(v.y);
        sA1[r*40 + c + 2] = f2h(v.z);
        sA1[r*40 + c + 3] = f2h(v.w);
        float4 w = *(const float4*)(x2 + (size_t)(row0 + r) * 32 + c);
        sX2[r*33 + c] = w.x; sX2[r*33 + c + 1] = w.y;
        sX2[r*33 + c + 2] = w.z; sX2[r*33 + c + 3] = w.w;
    }
    __syncthreads();

    // ---- phase 1: h1 = relu(x1 @ W1 + b1); K=32 = one MFMA ----
    {
        half8 a0 = *(const half8*)(sA1 + ln * 40 + kg * 8);
        half8 a1 = *(const half8*)(sA1 + (16 + ln) * 40 + kg * 8);
        #pragma unroll
        for (int nt = 0; nt < 4; ++nt) {
            int n = wave * 64 + nt * 16 + ln;
            half8 bfr = *(const half8*)(W1T + n * 32 + kg * 8);
            f32x4 zr = {0.f, 0.f, 0.f, 0.f};
            f32x4 c0 = MFMA16(a0, bfr, zr);
            f32x4 c1 = MFMA16(a1, bfr, zr);
            float bias = b1[n];
            #pragma unroll
            for (int g = 0; g < 4; ++g) {
                sH1[(kg*4 + g) * 264 + n]      = f2h(fmaxf(c0[g] + bias, 0.f));
                sH1[(16 + kg*4 + g) * 264 + n] = f2h(fmaxf(c1[g] + bias, 0.f));
            }
        }
    }
    __syncthreads();

    // ---- phase 2: h2 = relu(h1 @ W2 + b2); K=256 ----
    {
        half8 a0[8], a1[8];
        #pragma unroll
        for (int ks = 0; ks < 8; ++ks) {
            a0[ks] = *(const half8*)(sH1 + ln * 264 + ks * 32 + kg * 8);
            a1[ks] = *(const half8*)(sH1 + (16 + ln) * 264 + ks * 32 + kg * 8);
        }
        #pragma unroll
        for (int nt = 0; nt < 4; ++nt) {
            int n = wave * 64 + nt * 16 + ln;
            f32x4 c0 = {0,0,0,0}, c1 = {0,0,0,0};
            const ushort* bp = W2T + (size_t)n * 256 + kg * 8;
            #pragma unroll
            for (int ks = 0; ks < 8; ++ks) {
                half8 bfr = *(const half8*)(bp + ks * 32);
                c0 = MFMA16(a0[ks], bfr, c0);
                c1 = MFMA16(a1[ks], bfr, c1);
            }
            float bias = b2[n];
            #pragma unroll
            for (int g = 0; g < 4; ++g) {
                sH2[(kg*4 + g) * 264 + n]      = f2h(fmaxf(c0[g] + bias, 0.f));
                sH2[(16 + kg*4 + g) * 264 + n] = f2h(fmaxf(c1[g] + bias, 0.f));
            }
        }
    }
    __syncthreads();

    // ---- phase 3: hoist GEMM3 A-fragments to registers, free sH2 for sPw ----
    half8 A0[8], A1[8];
    #pragma unroll
    for (int ks = 0; ks < 8; ++ks) {
        A0[ks] = *(const half8*)(sH2 + ln * 264 + ks * 32 + kg * 8);
        A1[ks] = *(const half8*)(sH2 + (16 + ln) * 264 + ks * 32 + kg * 8);
    }
    __syncthreads();   // all waves done reading sH2 before sPw overwrites it

    // ---- phase 4: GEMM3 (N padded 2048, 64 cols/dim) + fused spline ----
    // wave owns dims [wave*8, wave*8+8); 2 dims (8 N-tiles) per chunk.
    // B-fragments double-buffered in registers across nt to overlap L2 latency.
    float* myP = sPw + wave * (32 * 101);
    for (int dc = 0; dc < 4; ++dc) {
        const int nb = (wave * 8 + dc * 2) * 64;

        float bias[8];
        #pragma unroll
        for (int nt = 0; nt < 8; ++nt) bias[nt] = b3p[nb + nt * 16 + ln];

        half8 bcur[8], bnxt[8];
        {
            const ushort* bp = W3T + (size_t)(nb + ln) * 256 + kg * 8;
            #pragma unroll
            for (int ks = 0; ks < 8; ++ks) bcur[ks] = *(const half8*)(bp + ks * 32);
        }

        #pragma unroll
        for (int nt = 0; nt < 8; ++nt) {
            if (nt < 7) {
                const ushort* bp = W3T + (size_t)(nb + (nt + 1) * 16 + ln) * 256 + kg * 8;
                #pragma unroll
                for (int ks = 0; ks < 8; ++ks) bnxt[ks] = *(const half8*)(bp + ks * 32);
            }
            f32x4 c0 = {0,0,0,0}, c1 = {0,0,0,0};
            #pragma unroll
            for (int ks = 0; ks < 8; ++ks) {
                c0 = MFMA16(A0[ks], bcur[ks], c0);
                c1 = MFMA16(A1[ks], bcur[ks], c1);
            }
            int lc = nt * 16 + ln;
            int dd = lc >> 6, p = lc & 63;
            if (p < 49) {
                #pragma unroll
                for (int g = 0; g < 4; ++g) {
                    myP[(kg*4 + g) * 101 + dd * 50 + p]      = c0[g] + bias[nt];
                    myP[(16 + kg*4 + g) * 101 + dd * 50 + p] = c1[g] + bias[nt];
                }
            }
            if (nt < 7) {
                #pragma unroll
                for (int ks = 0; ks < 8; ++ks) bcur[ks] = bnxt[ks];
            }
        }

        // spline: 32 rows x 2 dims = 1 task/lane, wave-local fp32 params.
        // No barrier: myP is wave-private, DS ops in-order per wave.
        {
            const int r = lane >> 1, dd = lane & 1;
            const int dim = wave * 8 + dc * 2 + dd;
            const float* pp = myP + r * 101 + dd * 50;
            const float x  = sX2[r * 33 + dim];
            const float xc = fminf(fmaxf(x, -TAILV), TAILV);

            float e[NB]; float mx = -1e30f;
            #pragma unroll
            for (int k = 0; k < NB; ++k) { e[k] = pp[k]; mx = fmaxf(mx, e[k]); }
            float s = 0.f;
            #pragma unroll
            for (int k = 0; k < NB; ++k) { e[k] = expf(e[k] - mx); s += e[k]; }
            const float inv = 1.f / s;

            int idx = 0; float xk = -TAILV, xk1 = TAILV, cum = 0.f;
            #pragma unroll
            for (int k = 0; k < NB; ++k) {
                float lo = -TAILV + 2.f * TAILV * cum;
                cum += MINV + CSC * e[k] * inv;
                float hi = -TAILV + 2.f * TAILV * cum;
                if (lo <= xc) { idx = k; xk = lo; xk1 = hi; }
            }

            float eh[NB]; float mh = -1e30f;
            #pragma unroll
            for (int k = 0; k < NB; ++k) { eh[k] = pp[NB + k]; mh = fmaxf(mh, eh[k]); }
            float sh = 0.f;
            #pragma unroll
            for (int k = 0; k < NB; ++k) { eh[k] = expf(eh[k] - mh); sh += eh[k]; }
            const float invh = 1.f / sh;

            float yk = -TAILV, yk1 = TAILV; cum = 0.f;
            #pragma unroll
            for (int k = 0; k < NB; ++k) {
                float lo = -TAILV + 2.f * TAILV * cum;
                cum += MINV + CSC * eh[k] * invh;
                float hi = -TAILV + 2.f * TAILV * cum;
                if (k == idx) { yk = lo; yk1 = hi; }
            }

            const float d0 = MINV + softplus_f(pp[2 * NB + idx]);
            const float d1 = MINV + softplus_f(pp[2 * NB + idx + 1]);

            const float wd = xk1 - xk, hd = yk1 - yk;
            const float sk = hd / wd;
            const float xi = (xc - xk) / wd;
            const float xim = xi * (1.f - xi);
            const float alpha = hd * (sk * xi * xi + d0 * xim);
            const float beta  = sk + (d1 + d0 - 2.f * sk) * xim;
            const float z     = yk + alpha / beta;
            const float om    = 1.f - xi;
            const float dn    = sk * sk * (d1 * xi * xi + 2.f * sk * xim + d0 * om * om);
            const float ld    = logf(dn) - 2.f * logf(beta);

            const bool inside = (x >= -TAILV) && (x <= TAILV);
            zout[(size_t)(row0 + r) * 32 + dim] = inside ? z : x;
            sLD[r * 33 + dim] = inside ? ld : 0.f;
        }
    }
    __syncthreads();   // sLD complete across all waves

    // ---- phase 5: log_det reduction ----
    if (tid < 32) {
        float sld = 0.f;
        #pragma unroll
        for (int j = 0; j < 32; ++j) sld += sLD[tid * 33 + j];
        ldout[row0 + tid] = sld;
    }
}

extern "C" void kernel_launch(void* const* d_in, const int* in_sizes, int n_in,
                              void* d_out, int out_size, void* d_ws, size_t ws_size,
                              hipStream_t stream)
{
    const float* x1 = (const float*)d_in[0];
    const float* x2 = (const float*)d_in[1];
    const float* W1 = (const float*)d_in[2];
    const float* b1 = (const float*)d_in[3];
    const float* W2 = (const float*)d_in[4];
    const float* b2 = (const float*)d_in[5];
    const float* W3 = (const float*)d_in[6];
    const float* b3 = (const float*)d_in[7];

    // d_ws layout (1,204,224 B total)
    ushort* W3T = (ushort*)d_ws;                 // 2048*256 fp16 = 1 MB
    ushort* W2T = W3T + 2048 * 256;              // 256*256 fp16
    ushort* W1T = W2T + 256 * 256;               // 256*32 fp16
    float*  b3p = (float*)(W1T + 256 * 32);      // 2048 f32

    float* zout  = (float*)d_out;                // (65536, 32)
    float* ldout = zout + (size_t)65536 * 32;    // (65536,)

    cvt_weights<<<2336, 256, 0, stream>>>(W1, W2, W3, b3, W3T, W2T, W1T, b3p);
    rq_mfma<<<2048, 256, 0, stream>>>(x1, x2, b1, b2, W1T, W2T, W3T, b3p, zout, ldout);
}

// Round 9
// 240.530 us; speedup vs baseline: 5.7538x; 1.4723x over previous
//
#include <hip/hip_runtime.h>
#include <cmath>

#define NB 16
#define TAILV 3.0f
#define MINV 0.001f
#define CSC 0.984f   // 1 - NB*MINV

typedef __attribute__((ext_vector_type(8))) _Float16 half8;
typedef __attribute__((ext_vector_type(4))) float f32x4;

#define MFMA16(a,b,c) __builtin_amdgcn_mfma_f32_16x16x32_f16(a,b,c,0,0,0)

__device__ __forceinline__ ushort f2h(float f) {
    union { _Float16 h; ushort u; } v; v.h = (_Float16)f; return v.u;
}
__device__ __forceinline__ float softplus_f(float x) {
    return (x > 20.0f) ? x : log1pf(expf(x));
}

// ---- prologue: convert/transpose weights into d_ws (fp16, [N][K]) ----
// W3T: [2048][256], n = dim*64 + p (p<49 real, else 0).  W2T: [256][256].  W1T: [256][32].
__global__ void __launch_bounds__(256)
cvt_weights(const float* __restrict__ W1, const float* __restrict__ W2,
            const float* __restrict__ W3, const float* __restrict__ b3,
            ushort* __restrict__ W3T, ushort* __restrict__ W2T,
            ushort* __restrict__ W1T, float* __restrict__ b3p)
{
    const int b = blockIdx.x, t = threadIdx.x;
    if (b < 2048) {
        int idx = b * 256 + t;
        int n = idx >> 8, k = idx & 255;
        int dim = n >> 6, p = n & 63;
        float v = (p < 49) ? W3[(size_t)k * 1568 + dim * 49 + p] : 0.0f;
        W3T[idx] = f2h(v);
        if (k == 0) b3p[n] = (p < 49) ? b3[dim * 49 + p] : 0.0f;
    } else if (b < 2048 + 256) {
        int idx = (b - 2048) * 256 + t;
        int n = idx >> 8, k = idx & 255;
        W2T[idx] = f2h(W2[(size_t)k * 256 + n]);
    } else {   // 32 blocks for W1 (8192 elems)
        int idx = (b - 2304) * 256 + t;
        int n = idx >> 5, k = idx & 31;
        W1T[idx] = f2h(W1[(size_t)k * 256 + n]);
    }
}

// ---- fused main kernel: 64 batch rows / block, 4 waves, 1024 blocks ----
// TM=64 halves W3T L2 traffic (each block streams the 1 MB W3T once) and
// doubles MFMA per B-load. Staging ping-pong: h1 rows 0-31->R0, 32-63->R1;
// h2 rows 0-31->R2 (over dead sA1), rows 32-63->R0 (after barrier).
// Phase 4: A-frags in 128 VGPRs; chunks of 1 dim -> 64-lane spline (1 task/lane),
// log_det accumulated in registers; next chunk's B-loads prefetched before spline.
extern "C" __global__ void __launch_bounds__(256, 2)
rq_mfma(const float* __restrict__ x1, const float* __restrict__ x2,
        const float* __restrict__ b1, const float* __restrict__ b2,
        const ushort* __restrict__ W1T, const ushort* __restrict__ W2T,
        const ushort* __restrict__ W3T, const float* __restrict__ b3p,
        float* __restrict__ zout, float* __restrict__ ldout)
{
    __shared__ char smem[60416];
    float*  sX2  = (float*)smem;                    // [64][33] f32 = 8448
    float*  sLDw = (float*)(smem + 8448);           // [64][5] f32 = 1280
    char*   U    = smem + 9728;                     // 50688-byte union
    ushort* R0   = (ushort*)U;                      // [32][264] fp16 = 16896
    ushort* R1   = (ushort*)(U + 16896);            // [32][264]
    ushort* R2   = (ushort*)(U + 33792);            // [32][264]
    ushort* sA1  = R2;                              // [64][40] fp16 = 5120
    float*  sPw  = (float*)U;                       // 4 x [64][49] f32 = 50176

    const int tid  = threadIdx.x;
    const int row0 = blockIdx.x * 64;
    const int wave = tid >> 6, lane = tid & 63;
    const int ln = lane & 15, kg = lane >> 4;       // frag: m/n=ln, k-group=kg

    // ---- phase 0: stage x1 (->fp16, R2) and x2 (f32) ----
    {
        int r = tid >> 2, c = (tid & 3) << 3;
        float4 v0 = *(const float4*)(x1 + (size_t)(row0 + r) * 32 + c);
        float4 v1 = *(const float4*)(x1 + (size_t)(row0 + r) * 32 + c + 4);
        sA1[r*40 + c    ] = f2h(v0.x); sA1[r*40 + c + 1] = f2h(v0.y);
        sA1[r*40 + c + 2] = f2h(v0.z); sA1[r*40 + c + 3] = f2h(v0.w);
        sA1[r*40 + c + 4] = f2h(v1.x); sA1[r*40 + c + 5] = f2h(v1.y);
        sA1[r*40 + c + 6] = f2h(v1.z); sA1[r*40 + c + 7] = f2h(v1.w);
        float4 w0 = *(const float4*)(x2 + (size_t)(row0 + r) * 32 + c);
        float4 w1 = *(const float4*)(x2 + (size_t)(row0 + r) * 32 + c + 4);
        sX2[r*33 + c    ] = w0.x; sX2[r*33 + c + 1] = w0.y;
        sX2[r*33 + c + 2] = w0.z; sX2[r*33 + c + 3] = w0.w;
        sX2[r*33 + c + 4] = w1.x; sX2[r*33 + c + 5] = w1.y;
        sX2[r*33 + c + 6] = w1.z; sX2[r*33 + c + 7] = w1.w;
    }
    __syncthreads();

    // ---- phase 1: h1 = relu(x1 @ W1 + b1); 4 M-tiles, K=32 ----
    {
        half8 a[4];
        #pragma unroll
        for (int m = 0; m < 4; ++m)
            a[m] = *(const half8*)(sA1 + (m*16 + ln)*40 + kg*8);
        #pragma unroll
        for (int nt = 0; nt < 4; ++nt) {
            int n = wave*64 + nt*16 + ln;
            half8 bfr = *(const half8*)(W1T + n*32 + kg*8);
            float bias = b1[n];
            f32x4 zr = {0.f,0.f,0.f,0.f};
            #pragma unroll
            for (int m = 0; m < 4; ++m) {
                f32x4 cm = MFMA16(a[m], bfr, zr);
                ushort* dst = (m < 2) ? R0 : R1;
                int rb = (m & 1) * 16;
                #pragma unroll
                for (int g = 0; g < 4; ++g)
                    dst[(rb + kg*4 + g)*264 + n] = f2h(fmaxf(cm[g] + bias, 0.f));
            }
        }
    }
    __syncthreads();

    // ---- phase 2: h2 = relu(h1 @ W2 + b2), two 32-row half-passes ----
    #pragma unroll
    for (int part = 0; part < 2; ++part) {
        const ushort* S = (part == 0) ? R0 : R1;   // h1 rows
        ushort*       D = (part == 0) ? R2 : R0;   // h2 rows
        half8 a0[8], a1[8];
        #pragma unroll
        for (int ks = 0; ks < 8; ++ks) {
            a0[ks] = *(const half8*)(S + ln*264 + ks*32 + kg*8);
            a1[ks] = *(const half8*)(S + (16 + ln)*264 + ks*32 + kg*8);
        }
        #pragma unroll
        for (int nt = 0; nt < 4; ++nt) {
            int n = wave*64 + nt*16 + ln;
            f32x4 c0 = {0,0,0,0}, c1 = {0,0,0,0};
            const ushort* bp = W2T + (size_t)n*256 + kg*8;
            #pragma unroll
            for (int ks = 0; ks < 8; ++ks) {
                half8 bfr = *(const half8*)(bp + ks*32);
                c0 = MFMA16(a0[ks], bfr, c0);
                c1 = MFMA16(a1[ks], bfr, c1);
            }
            float bias = b2[n];
            #pragma unroll
            for (int g = 0; g < 4; ++g) {
                D[(kg*4 + g)*264 + n]      = f2h(fmaxf(c0[g] + bias, 0.f));
                D[(16 + kg*4 + g)*264 + n] = f2h(fmaxf(c1[g] + bias, 0.f));
            }
        }
        __syncthreads();
    }

    // ---- phase 3: hoist GEMM3 A-fragments (4 M-tiles x 8 ks = 128 VGPR) ----
    half8 A[4][8];
    #pragma unroll
    for (int m = 0; m < 4; ++m) {
        const ushort* src = (m < 2) ? R2 : R0;     // h2 rows 0-31 / 32-63
        int rb = (m & 1) * 16;
        #pragma unroll
        for (int ks = 0; ks < 8; ++ks)
            A[m][ks] = *(const half8*)(src + (rb + ln)*264 + ks*32 + kg*8);
    }
    __syncthreads();   // staging dead; sPw overlays U

    // ---- phase 4: GEMM3 + fused spline; wave owns dims [wave*8, wave*8+8) ----
    float* myP = sPw + wave * (64 * 49);
    float  ldacc = 0.f;

    half8 bcur[8], bnxt[8];
    {
        int n0 = (wave*8)*64 + ln;
        const ushort* bp = W3T + (size_t)n0*256 + kg*8;
        #pragma unroll
        for (int ks = 0; ks < 8; ++ks) bcur[ks] = *(const half8*)(bp + ks*32);
    }

    for (int ch = 0; ch < 8; ++ch) {
        const int dim = wave*8 + ch;
        const int nb  = dim * 64;
        float bias[4];
        #pragma unroll
        for (int nt = 0; nt < 4; ++nt) bias[nt] = b3p[nb + nt*16 + ln];

        #pragma unroll
        for (int nt = 0; nt < 4; ++nt) {
            int t = ch*4 + nt;
            if (t < 31) {   // prefetch next tile (incl. next chunk's first, pre-spline)
                int tn = t + 1;
                int nn = (wave*8 + (tn >> 2))*64 + (tn & 3)*16 + ln;
                const ushort* bp = W3T + (size_t)nn*256 + kg*8;
                #pragma unroll
                for (int ks = 0; ks < 8; ++ks) bnxt[ks] = *(const half8*)(bp + ks*32);
            }
            f32x4 c[4];
            #pragma unroll
            for (int m = 0; m < 4; ++m) c[m] = (f32x4){0,0,0,0};
            #pragma unroll
            for (int ks = 0; ks < 8; ++ks)
                #pragma unroll
                for (int m = 0; m < 4; ++m)
                    c[m] = MFMA16(A[m][ks], bcur[ks], c[m]);
            int p = nt*16 + ln;
            if (p < 49) {
                #pragma unroll
                for (int m = 0; m < 4; ++m)
                    #pragma unroll
                    for (int g = 0; g < 4; ++g)
                        myP[(m*16 + kg*4 + g)*49 + p] = c[m][g] + bias[nt];
            }
            if (t < 31) {
                #pragma unroll
                for (int ks = 0; ks < 8; ++ks) bcur[ks] = bnxt[ks];
            }
        }

        // spline: 64 rows x 1 dim = exactly 1 task/lane (r = lane)
        {
            const float* pp = myP + lane * 49;
            const float x  = sX2[lane*33 + dim];
            const float xc = fminf(fmaxf(x, -TAILV), TAILV);

            float e[NB]; float mx = -1e30f;
            #pragma unroll
            for (int k = 0; k < NB; ++k) { e[k] = pp[k]; mx = fmaxf(mx, e[k]); }
            float s = 0.f;
            #pragma unroll
            for (int k = 0; k < NB; ++k) { e[k] = expf(e[k] - mx); s += e[k]; }
            const float inv = 1.f / s;

            int idx = 0; float xk = -TAILV, xk1 = TAILV, cum = 0.f;
            #pragma unroll
            for (int k = 0; k < NB; ++k) {
                float lo = -TAILV + 2.f * TAILV * cum;
                cum += MINV + CSC * e[k] * inv;
                float hi = -TAILV + 2.f * TAILV * cum;
                if (lo <= xc) { idx = k; xk = lo; xk1 = hi; }
            }

            float eh[NB]; float mh = -1e30f;
            #pragma unroll
            for (int k = 0; k < NB; ++k) { eh[k] = pp[NB + k]; mh = fmaxf(mh, eh[k]); }
            float sh = 0.f;
            #pragma unroll
            for (int k = 0; k < NB; ++k) { eh[k] = expf(eh[k] - mh); sh += eh[k]; }
            const float invh = 1.f / sh;

            float yk = -TAILV, yk1 = TAILV; cum = 0.f;
            #pragma unroll
            for (int k = 0; k < NB; ++k) {
                float lo = -TAILV + 2.f * TAILV * cum;
                cum += MINV + CSC * eh[k] * invh;
                float hi = -TAILV + 2.f * TAILV * cum;
                if (k == idx) { yk = lo; yk1 = hi; }
            }

            const float d0 = MINV + softplus_f(pp[2*NB + idx]);
            const float d1 = MINV + softplus_f(pp[2*NB + idx + 1]);

            const float wd = xk1 - xk, hd = yk1 - yk;
            const float sk = hd / wd;
            const float xi = (xc - xk) / wd;
            const float xim = xi * (1.f - xi);
            const float alpha = hd * (sk * xi * xi + d0 * xim);
            const float beta  = sk + (d1 + d0 - 2.f * sk) * xim;
            const float z     = yk + alpha / beta;
            const float om    = 1.f - xi;
            const float dn    = sk * sk * (d1 * xi * xi + 2.f * sk * xim + d0 * om * om);
            const float ld    = logf(dn) - 2.f * logf(beta);

            const bool inside = (x >= -TAILV) && (x <= TAILV);
            zout[(size_t)(row0 + lane) * 32 + dim] = inside ? z : x;
            ldacc += inside ? ld : 0.f;
        }
    }
    sLDw[lane*5 + wave] = ldacc;
    __syncthreads();

    // ---- phase 5: log_det reduction across waves ----
    if (tid < 64) {
        float sld = sLDw[tid*5 + 0] + sLDw[tid*5 + 1]
                  + sLDw[tid*5 + 2] + sLDw[tid*5 + 3];
        ldout[row0 + tid] = sld;
    }
}

extern "C" void kernel_launch(void* const* d_in, const int* in_sizes, int n_in,
                              void* d_out, int out_size, void* d_ws, size_t ws_size,
                              hipStream_t stream)
{
    const float* x1 = (const float*)d_in[0];
    const float* x2 = (const float*)d_in[1];
    const float* W1 = (const float*)d_in[2];
    const float* b1 = (const float*)d_in[3];
    const float* W2 = (const float*)d_in[4];
    const float* b2 = (const float*)d_in[5];
    const float* W3 = (const float*)d_in[6];
    const float* b3 = (const float*)d_in[7];

    // d_ws layout (1,204,224 B total)
    ushort* W3T = (ushort*)d_ws;                 // 2048*256 fp16 = 1 MB
    ushort* W2T = W3T + 2048 * 256;              // 256*256 fp16
    ushort* W1T = W2T + 256 * 256;               // 256*32 fp16
    float*  b3p = (float*)(W1T + 256 * 32);      // 2048 f32

    float* zout  = (float*)d_out;                // (65536, 32)
    float* ldout = zout + (size_t)65536 * 32;    // (65536,)

    cvt_weights<<<2336, 256, 0, stream>>>(W1, W2, W3, b3, W3T, W2T, W1T, b3p);
    rq_mfma<<<1024, 256, 0, stream>>>(x1, x2, b1, b2, W1T, W2T, W3T, b3p, zout, ldout);
}

// Round 10
// 232.136 us; speedup vs baseline: 5.9619x; 1.0362x over previous
//
#include <hip/hip_runtime.h>
#include <cmath>

#define NB 16
#define TAILV 3.0f
#define MINV 0.001f
#define CSC 0.984f   // 1 - NB*MINV

typedef __attribute__((ext_vector_type(8))) _Float16 half8;
typedef __attribute__((ext_vector_type(4))) float f32x4;

#define MFMA16(a,b,c) __builtin_amdgcn_mfma_f32_16x16x32_f16(a,b,c,0,0,0)

__device__ __forceinline__ ushort f2h(float f) {
    union { _Float16 h; ushort u; } v; v.h = (_Float16)f; return v.u;
}
__device__ __forceinline__ float softplus_f(float x) {
    return (x > 20.0f) ? x : __logf(1.0f + __expf(x));   // fast-math: margin 0.375->0.76 absorbs ~ulp error
}

// ---- prologue: convert/transpose weights into d_ws (fp16, [N][K]) ----
// W3T: [2048][256], n = dim*64 + p (p<49 real, else 0).  W2T: [256][256].  W1T: [256][32].
__global__ void __launch_bounds__(256)
cvt_weights(const float* __restrict__ W1, const float* __restrict__ W2,
            const float* __restrict__ W3, const float* __restrict__ b3,
            ushort* __restrict__ W3T, ushort* __restrict__ W2T,
            ushort* __restrict__ W1T, float* __restrict__ b3p)
{
    const int b = blockIdx.x, t = threadIdx.x;
    if (b < 2048) {
        int idx = b * 256 + t;
        int n = idx >> 8, k = idx & 255;
        int dim = n >> 6, p = n & 63;
        float v = (p < 49) ? W3[(size_t)k * 1568 + dim * 49 + p] : 0.0f;
        W3T[idx] = f2h(v);
        if (k == 0) b3p[n] = (p < 49) ? b3[dim * 49 + p] : 0.0f;
    } else if (b < 2048 + 256) {
        int idx = (b - 2048) * 256 + t;
        int n = idx >> 8, k = idx & 255;
        W2T[idx] = f2h(W2[(size_t)k * 256 + n]);
    } else {   // 32 blocks for W1 (8192 elems)
        int idx = (b - 2304) * 256 + t;
        int n = idx >> 5, k = idx & 31;
        W1T[idx] = f2h(W1[(size_t)k * 256 + n]);
    }
}

// ---- fused main kernel: 64 batch rows / block, 4 waves, 1024 blocks ----
// Phase-4 chunk order rotated by blockIdx&7 so co-resident blocks stream
// different W3T regions (de-correlate L2 request streams).
extern "C" __global__ void __launch_bounds__(256, 2)
rq_mfma(const float* __restrict__ x1, const float* __restrict__ x2,
        const float* __restrict__ b1, const float* __restrict__ b2,
        const ushort* __restrict__ W1T, const ushort* __restrict__ W2T,
        const ushort* __restrict__ W3T, const float* __restrict__ b3p,
        float* __restrict__ zout, float* __restrict__ ldout)
{
    __shared__ char smem[60416];
    float*  sX2  = (float*)smem;                    // [64][33] f32 = 8448
    float*  sLDw = (float*)(smem + 8448);           // [64][5] f32 = 1280
    char*   U    = smem + 9728;                     // 50688-byte union
    ushort* R0   = (ushort*)U;                      // [32][264] fp16 = 16896
    ushort* R1   = (ushort*)(U + 16896);            // [32][264]
    ushort* R2   = (ushort*)(U + 33792);            // [32][264]
    ushort* sA1  = R2;                              // [64][40] fp16 = 5120
    float*  sPw  = (float*)U;                       // 4 x [64][49] f32 = 50176

    const int tid  = threadIdx.x;
    const int row0 = blockIdx.x * 64;
    const int rot  = blockIdx.x & 7;
    const int wave = tid >> 6, lane = tid & 63;
    const int ln = lane & 15, kg = lane >> 4;       // frag: m/n=ln, k-group=kg

    // ---- phase 0: stage x1 (->fp16, R2) and x2 (f32) ----
    {
        int r = tid >> 2, c = (tid & 3) << 3;
        float4 v0 = *(const float4*)(x1 + (size_t)(row0 + r) * 32 + c);
        float4 v1 = *(const float4*)(x1 + (size_t)(row0 + r) * 32 + c + 4);
        sA1[r*40 + c    ] = f2h(v0.x); sA1[r*40 + c + 1] = f2h(v0.y);
        sA1[r*40 + c + 2] = f2h(v0.z); sA1[r*40 + c + 3] = f2h(v0.w);
        sA1[r*40 + c + 4] = f2h(v1.x); sA1[r*40 + c + 5] = f2h(v1.y);
        sA1[r*40 + c + 6] = f2h(v1.z); sA1[r*40 + c + 7] = f2h(v1.w);
        float4 w0 = *(const float4*)(x2 + (size_t)(row0 + r) * 32 + c);
        float4 w1 = *(const float4*)(x2 + (size_t)(row0 + r) * 32 + c + 4);
        sX2[r*33 + c    ] = w0.x; sX2[r*33 + c + 1] = w0.y;
        sX2[r*33 + c + 2] = w0.z; sX2[r*33 + c + 3] = w0.w;
        sX2[r*33 + c + 4] = w1.x; sX2[r*33 + c + 5] = w1.y;
        sX2[r*33 + c + 6] = w1.z; sX2[r*33 + c + 7] = w1.w;
    }
    __syncthreads();

    // ---- phase 1: h1 = relu(x1 @ W1 + b1); 4 M-tiles, K=32 ----
    {
        half8 a[4];
        #pragma unroll
        for (int m = 0; m < 4; ++m)
            a[m] = *(const half8*)(sA1 + (m*16 + ln)*40 + kg*8);
        #pragma unroll
        for (int nt = 0; nt < 4; ++nt) {
            int n = wave*64 + nt*16 + ln;
            half8 bfr = *(const half8*)(W1T + n*32 + kg*8);
            float bias = b1[n];
            f32x4 zr = {0.f,0.f,0.f,0.f};
            #pragma unroll
            for (int m = 0; m < 4; ++m) {
                f32x4 cm = MFMA16(a[m], bfr, zr);
                ushort* dst = (m < 2) ? R0 : R1;
                int rb = (m & 1) * 16;
                #pragma unroll
                for (int g = 0; g < 4; ++g)
                    dst[(rb + kg*4 + g)*264 + n] = f2h(fmaxf(cm[g] + bias, 0.f));
            }
        }
    }
    __syncthreads();

    // ---- phase 2: h2 = relu(h1 @ W2 + b2), two 32-row half-passes ----
    #pragma unroll
    for (int part = 0; part < 2; ++part) {
        const ushort* S = (part == 0) ? R0 : R1;   // h1 rows
        ushort*       D = (part == 0) ? R2 : R0;   // h2 rows
        half8 a0[8], a1[8];
        #pragma unroll
        for (int ks = 0; ks < 8; ++ks) {
            a0[ks] = *(const half8*)(S + ln*264 + ks*32 + kg*8);
            a1[ks] = *(const half8*)(S + (16 + ln)*264 + ks*32 + kg*8);
        }
        #pragma unroll
        for (int nt = 0; nt < 4; ++nt) {
            int n = wave*64 + nt*16 + ln;
            f32x4 c0 = {0,0,0,0}, c1 = {0,0,0,0};
            const ushort* bp = W2T + (size_t)n*256 + kg*8;
            #pragma unroll
            for (int ks = 0; ks < 8; ++ks) {
                half8 bfr = *(const half8*)(bp + ks*32);
                c0 = MFMA16(a0[ks], bfr, c0);
                c1 = MFMA16(a1[ks], bfr, c1);
            }
            float bias = b2[n];
            #pragma unroll
            for (int g = 0; g < 4; ++g) {
                D[(kg*4 + g)*264 + n]      = f2h(fmaxf(c0[g] + bias, 0.f));
                D[(16 + kg*4 + g)*264 + n] = f2h(fmaxf(c1[g] + bias, 0.f));
            }
        }
        __syncthreads();
    }

    // ---- phase 3: hoist GEMM3 A-fragments (4 M-tiles x 8 ks = 128 regs) ----
    half8 A[4][8];
    #pragma unroll
    for (int m = 0; m < 4; ++m) {
        const ushort* src = (m < 2) ? R2 : R0;     // h2 rows 0-31 / 32-63
        int rb = (m & 1) * 16;
        #pragma unroll
        for (int ks = 0; ks < 8; ++ks)
            A[m][ks] = *(const half8*)(src + (rb + ln)*264 + ks*32 + kg*8);
    }
    __syncthreads();   // staging dead; sPw overlays U

    // ---- phase 4: GEMM3 + fused spline; wave owns dims [wave*8, wave*8+8) ----
    float* myP = sPw + wave * (64 * 49);
    float  ldacc = 0.f;

    half8 bcur[8], bnxt[8];
    {
        int dim0 = wave*8 + rot;
        const ushort* bp = W3T + (size_t)(dim0*64 + ln)*256 + kg*8;
        #pragma unroll
        for (int ks = 0; ks < 8; ++ks) bcur[ks] = *(const half8*)(bp + ks*32);
    }

    for (int ch0 = 0; ch0 < 8; ++ch0) {
        const int ch  = (ch0 + rot) & 7;
        const int dim = wave*8 + ch;
        const int nb  = dim * 64;
        float bias[4];
        #pragma unroll
        for (int nt = 0; nt < 4; ++nt) bias[nt] = b3p[nb + nt*16 + ln];

        #pragma unroll
        for (int nt = 0; nt < 4; ++nt) {
            const bool last = (ch0 == 7) && (nt == 3);
            if (!last) {   // prefetch next tile (rotated order)
                int ndim = (nt == 3) ? (wave*8 + ((ch0 + 1 + rot) & 7)) : dim;
                int nnt  = (nt == 3) ? 0 : nt + 1;
                const ushort* bp = W3T + (size_t)(ndim*64 + nnt*16 + ln)*256 + kg*8;
                #pragma unroll
                for (int ks = 0; ks < 8; ++ks) bnxt[ks] = *(const half8*)(bp + ks*32);
            }
            f32x4 c[4];
            #pragma unroll
            for (int m = 0; m < 4; ++m) c[m] = (f32x4){0,0,0,0};
            #pragma unroll
            for (int ks = 0; ks < 8; ++ks)
                #pragma unroll
                for (int m = 0; m < 4; ++m)
                    c[m] = MFMA16(A[m][ks], bcur[ks], c[m]);
            int p = nt*16 + ln;
            if (p < 49) {
                #pragma unroll
                for (int m = 0; m < 4; ++m)
                    #pragma unroll
                    for (int g = 0; g < 4; ++g)
                        myP[(m*16 + kg*4 + g)*49 + p] = c[m][g] + bias[nt];
            }
            if (!last) {
                #pragma unroll
                for (int ks = 0; ks < 8; ++ks) bcur[ks] = bnxt[ks];
            }
        }

        // spline: 64 rows x 1 dim = exactly 1 task/lane (r = lane)
        {
            const float* pp = myP + lane * 49;
            const float x  = sX2[lane*33 + dim];
            const float xc = fminf(fmaxf(x, -TAILV), TAILV);

            float e[NB]; float mx = -1e30f;
            #pragma unroll
            for (int k = 0; k < NB; ++k) { e[k] = pp[k]; mx = fmaxf(mx, e[k]); }
            float s = 0.f;
            #pragma unroll
            for (int k = 0; k < NB; ++k) { e[k] = __expf(e[k] - mx); s += e[k]; }
            const float inv = 1.f / s;

            int idx = 0; float xk = -TAILV, xk1 = TAILV, cum = 0.f;
            #pragma unroll
            for (int k = 0; k < NB; ++k) {
                float lo = -TAILV + 2.f * TAILV * cum;
                cum += MINV + CSC * e[k] * inv;
                float hi = -TAILV + 2.f * TAILV * cum;
                if (lo <= xc) { idx = k; xk = lo; xk1 = hi; }
            }

            float eh[NB]; float mh = -1e30f;
            #pragma unroll
            for (int k = 0; k < NB; ++k) { eh[k] = pp[NB + k]; mh = fmaxf(mh, eh[k]); }
            float sh = 0.f;
            #pragma unroll
            for (int k = 0; k < NB; ++k) { eh[k] = __expf(eh[k] - mh); sh += eh[k]; }
            const float invh = 1.f / sh;

            float yk = -TAILV, yk1 = TAILV; cum = 0.f;
            #pragma unroll
            for (int k = 0; k < NB; ++k) {
                float lo = -TAILV + 2.f * TAILV * cum;
                cum += MINV + CSC * eh[k] * invh;
                float hi = -TAILV + 2.f * TAILV * cum;
                if (k == idx) { yk = lo; yk1 = hi; }
            }

            const float d0 = MINV + softplus_f(pp[2*NB + idx]);
            const float d1 = MINV + softplus_f(pp[2*NB + idx + 1]);

            const float wd = xk1 - xk, hd = yk1 - yk;
            const float sk = hd / wd;
            const float xi = (xc - xk) / wd;
            const float xim = xi * (1.f - xi);
            const float alpha = hd * (sk * xi * xi + d0 * xim);
            const float beta  = sk + (d1 + d0 - 2.f * sk) * xim;
            const float z     = yk + alpha / beta;
            const float om    = 1.f - xi;
            const float dn    = sk * sk * (d1 * xi * xi + 2.f * sk * xim + d0 * om * om);
            const float ld    = __logf(dn) - 2.f * __logf(beta);

            const bool inside = (x >= -TAILV) && (x <= TAILV);
            zout[(size_t)(row0 + lane) * 32 + dim] = inside ? z : x;
            ldacc += inside ? ld : 0.f;
        }
    }
    sLDw[lane*5 + wave] = ldacc;
    __syncthreads();

    // ---- phase 5: log_det reduction across waves ----
    if (tid < 64) {
        float sld = sLDw[tid*5 + 0] + sLDw[tid*5 + 1]
                  + sLDw[tid*5 + 2] + sLDw[tid*5 + 3];
        ldout[row0 + tid] = sld;
    }
}

extern "C" void kernel_launch(void* const* d_in, const int* in_sizes, int n_in,
                              void* d_out, int out_size, void* d_ws, size_t ws_size,
                              hipStream_t stream)
{
    const float* x1 = (const float*)d_in[0];
    const float* x2 = (const float*)d_in[1];
    const float* W1 = (const float*)d_in[2];
    const float* b1 = (const float*)d_in[3];
    const float* W2 = (const float*)d_in[4];
    const float* b2 = (const float*)d_in[5];
    const float* W3 = (const float*)d_in[6];
    const float* b3 = (const float*)d_in[7];

    // d_ws layout (1,204,224 B total)
    ushort* W3T = (ushort*)d_ws;                 // 2048*256 fp16 = 1 MB
    ushort* W2T = W3T + 2048 * 256;              // 256*256 fp16
    ushort* W1T = W2T + 256 * 256;               // 256*32 fp16
    float*  b3p = (float*)(W1T + 256 * 32);      // 2048 f32

    float* zout  = (float*)d_out;                // (65536, 32)
    float* ldout = zout + (size_t)65536 * 32;    // (65536,)

    cvt_weights<<<2336, 256, 0, stream>>>(W1, W2, W3, b3, W3T, W2T, W1T, b3p);
    rq_mfma<<<1024, 256, 0, stream>>>(x1, x2, b1, b2, W1T, W2T, W3T, b3p, zout, ldout);
}